// Round 1
// baseline (2158.582 us; speedup 1.0000x reference)
//
#include <hip/hip_runtime.h>
#include <stdint.h>

#define DGRID 128
#define D3 (DGRID * DGRID * DGRID)
#define NBATCH 2
#define NPTS 150000
#define NROWS (NBATCH * NPTS)
#define NCH 64
#define EPSBN 1e-4f
#define SBLK 1024

static __device__ __forceinline__ uint32_t f2bf_rne(float f) {
  uint32_t b = __float_as_uint(f);
  return (b + 0x7FFFu + ((b >> 16) & 1u)) >> 16;
}

// scatter point indices into dense voxel LUT (codes are unique per sample)
__global__ void k_scatter(const int* __restrict__ pos, int* __restrict__ lut) {
  int g = blockIdx.x * blockDim.x + threadIdx.x;
  if (g >= NROWS) return;
  int b = g / NPTS;
  int i = g - b * NPTS;
  int x = pos[3 * g], y = pos[3 * g + 1], z = pos[3 * g + 2];
  lut[(size_t)b * D3 + (x * DGRID + y) * DGRID + z] = i;
}

// compacted neighbor list per point: entries (tap<<18)|sample_local_idx
__global__ void k_nbr(const int* __restrict__ pos, const int* __restrict__ lut,
                      int* __restrict__ cnt, int* __restrict__ nbrp) {
  int g = blockIdx.x * blockDim.x + threadIdx.x;
  if (g >= NROWS) return;
  int b = g / NPTS;
  int x = pos[3 * g], y = pos[3 * g + 1], z = pos[3 * g + 2];
  const int* L = lut + (size_t)b * D3;
  int c = 0;
  int base = g * 27;
#pragma unroll
  for (int t = 0; t < 27; ++t) {
    int nx = x + t / 9 - 1;
    int ny = y + (t / 3) % 3 - 1;
    int nz = z + t % 3 - 1;
    if ((unsigned)nx < DGRID && (unsigned)ny < DGRID && (unsigned)nz < DGRID) {
      int n = L[(nx * DGRID + ny) * DGRID + nz];
      if (n >= 0) nbrp[base + (c++)] = (t << 18) | n;
    }
  }
  cnt[g] = c;
}

// pack W[conv][tap][cin][cout] f32 -> bf16, 4 consecutive cin per (uint2, cout)
// layout: Wp2[((conv*27+t)*16 + k2)*64 + cout] = {pack(cin 4k2,4k2+1), pack(4k2+2,4k2+3)}
__global__ void k_wpack(const float* __restrict__ Ws, uint2* __restrict__ Wp) {
  int g = blockIdx.x * blockDim.x + threadIdx.x;
  if (g >= 4 * 27 * 16 * 64) return;
  int lane = g & 63;
  int k2 = (g >> 6) & 15;
  int tt = g >> 10;  // conv*27+t
  const float* src = Ws + (size_t)tt * 64 * 64;
  uint32_t a0 = f2bf_rne(src[(4 * k2 + 0) * 64 + lane]);
  uint32_t a1 = f2bf_rne(src[(4 * k2 + 1) * 64 + lane]);
  uint32_t a2 = f2bf_rne(src[(4 * k2 + 2) * 64 + lane]);
  uint32_t a3 = f2bf_rne(src[(4 * k2 + 3) * 64 + lane]);
  uint2 u;
  u.x = (a1 << 16) | a0;
  u.y = (a3 << 16) | a2;
  Wp[g] = u;
}

// stage-1 BN stats: per-block partial sum/sumsq per channel
__global__ void k_stats1(const float* __restrict__ X, float* __restrict__ part) {
  __shared__ float s[512];
  int c = threadIdx.x & 63, q = threadIdx.x >> 6;
  float sm = 0.f, sq = 0.f;
  for (int r = blockIdx.x * 4 + q; r < NROWS; r += SBLK * 4) {
    float v = X[(size_t)r * 64 + c];
    sm += v;
    sq += v * v;
  }
  s[threadIdx.x] = sm;
  s[256 + threadIdx.x] = sq;
  __syncthreads();
  if (q == 0) {
    sm = s[c] + s[64 + c] + s[128 + c] + s[192 + c];
    sq = s[256 + c] + s[320 + c] + s[384 + c] + s[448 + c];
    part[blockIdx.x * 128 + c] = sm;
    part[blockIdx.x * 128 + 64 + c] = sq;
  }
}

// stage-2: finalize mean/var -> affine (a, b') so bnrelu(x) = relu(x*a + b')
__global__ void k_stats2(const float* __restrict__ part, const float* __restrict__ gamma,
                         const float* __restrict__ beta, float* __restrict__ chanp, int cid) {
  __shared__ float s[512];
  int c = threadIdx.x & 63, q = threadIdx.x >> 6;
  float sm = 0.f, sq = 0.f;
  for (int rb = q; rb < SBLK; rb += 4) {
    sm += part[rb * 128 + c];
    sq += part[rb * 128 + 64 + c];
  }
  s[threadIdx.x] = sm;
  s[256 + threadIdx.x] = sq;
  __syncthreads();
  if (q == 0) {
    sm = s[c] + s[64 + c] + s[128 + c] + s[192 + c];
    sq = s[256 + c] + s[320 + c] + s[384 + c] + s[448 + c];
    float mean = sm / (float)NROWS;
    float var = sq / (float)NROWS - mean * mean;
    float a = gamma[cid * 64 + c] * rsqrtf(var + EPSBN);
    chanp[cid * 128 + c] = a;
    chanp[cid * 128 + 64 + c] = beta[cid * 64 + c] - mean * a;
  }
}

// conv: wave per output point, lane = cout. BN+ReLU applied on the fly to
// gathered rows; cin broadcast via v_readlane (no LDS); W bf16-packed.
__global__ __launch_bounds__(256) void k_conv(
    const float* __restrict__ X, const uint2* __restrict__ Wp,
    const int* __restrict__ cnt, const int* __restrict__ nbrp,
    const float* __restrict__ chanp, int cid,
    const float* __restrict__ res, float* __restrict__ out) {
  int wid = (blockIdx.x * blockDim.x + threadIdx.x) >> 6;
  int lane = threadIdx.x & 63;
  if (wid >= NROWS) return;
  int b = wid / NPTS;
  float a = chanp[cid * 128 + lane];
  float bb = chanp[cid * 128 + 64 + lane];
  const uint2* Wbase = Wp + (size_t)cid * 27 * 1024;
  const float* Xb = X + (size_t)b * NPTS * 64;
  int n_nb = cnt[wid];
  int base = wid * 27;
  float acc0 = res ? res[(size_t)wid * 64 + lane] : 0.f;
  float acc1 = 0.f;
  for (int j = 0; j < n_nb; ++j) {
    uint32_t e = (uint32_t)nbrp[base + j];
    int t = (int)(e >> 18);
    int n = (int)(e & 0x3FFFFu);
    float y = Xb[(size_t)n * 64 + lane];
    y = fmaxf(fmaf(y, a, bb), 0.f);
    const uint2* Wt = Wbase + (size_t)t * 1024;
    uint32_t yu = __float_as_uint(y);
#pragma unroll
    for (int k = 0; k < 16; ++k) {
      uint2 w = Wt[k * 64 + lane];
      float w0 = __uint_as_float(w.x << 16);
      float w1 = __uint_as_float(w.x & 0xFFFF0000u);
      float w2 = __uint_as_float(w.y << 16);
      float w3 = __uint_as_float(w.y & 0xFFFF0000u);
      float y0 = __uint_as_float(__builtin_amdgcn_readlane(yu, 4 * k + 0));
      float y1 = __uint_as_float(__builtin_amdgcn_readlane(yu, 4 * k + 1));
      float y2 = __uint_as_float(__builtin_amdgcn_readlane(yu, 4 * k + 2));
      float y3 = __uint_as_float(__builtin_amdgcn_readlane(yu, 4 * k + 3));
      acc0 = fmaf(y0, w0, acc0);
      acc1 = fmaf(y1, w1, acc1);
      acc0 = fmaf(y2, w2, acc0);
      acc1 = fmaf(y3, w3, acc1);
    }
  }
  out[(size_t)wid * 64 + lane] = acc0 + acc1;
}

extern "C" void kernel_launch(void* const* d_in, const int* in_sizes, int n_in,
                              void* d_out, int out_size, void* d_ws, size_t ws_size,
                              hipStream_t stream) {
  const float* feats = (const float*)d_in[0];
  const float* Ws = (const float*)d_in[1];
  const float* gammas = (const float*)d_in[2];
  const float* betas = (const float*)d_in[3];
  const int* pos = (const int*)d_in[4];
  float* out = (float*)d_out;

  char* w = (char*)d_ws;
  auto alloc = [&](size_t bytes) {
    char* p = w;
    w += (bytes + 255) & ~(size_t)255;
    return p;
  };
  int* lut = (int*)alloc((size_t)NBATCH * D3 * 4);            // 16.8 MB
  int* cnt = (int*)alloc((size_t)NROWS * 4);                  // 1.2 MB
  int* nbrp = (int*)alloc((size_t)NROWS * 27 * 4);            // 32.4 MB
  uint2* Wp = (uint2*)alloc((size_t)4 * 27 * 1024 * 8);       // 0.9 MB
  float* part = (float*)alloc((size_t)SBLK * 128 * 4);        // 0.5 MB
  float* chanp = (float*)alloc((size_t)4 * 128 * 4);          // 2 KB
  float* cbuf = (float*)alloc((size_t)NROWS * 64 * 4);        // 76.8 MB

  hipMemsetAsync(lut, 0xFF, (size_t)NBATCH * D3 * 4, stream);
  int gpts = (NROWS + 255) / 256;
  k_scatter<<<gpts, 256, 0, stream>>>(pos, lut);
  k_nbr<<<gpts, 256, 0, stream>>>(pos, lut, cnt, nbrp);
  k_wpack<<<(4 * 27 * 16 * 64 + 255) / 256, 256, 0, stream>>>(Ws, Wp);

  int gconv = NROWS / 4;  // 4 waves (points) per 256-thread block
  for (int blk = 0; blk < 2; ++blk) {
    const float* X = blk ? (const float*)out : feats;
    int c0 = 2 * blk, c1 = 2 * blk + 1;
    k_stats1<<<SBLK, 256, 0, stream>>>(X, part);
    k_stats2<<<1, 256, 0, stream>>>(part, gammas, betas, chanp, c0);
    k_conv<<<gconv, 256, 0, stream>>>(X, Wp, cnt, nbrp, chanp, c0, nullptr, cbuf);
    k_stats1<<<SBLK, 256, 0, stream>>>(cbuf, part);
    k_stats2<<<1, 256, 0, stream>>>(part, gammas, betas, chanp, c1);
    k_conv<<<gconv, 256, 0, stream>>>(cbuf, Wp, cnt, nbrp, chanp, c1, X, out);
  }
}

// Round 2
// 1477.714 us; speedup vs baseline: 1.4608x; 1.4608x over previous
//
#include <hip/hip_runtime.h>
#include <stdint.h>

#define DGRID 128
#define D3 (DGRID * DGRID * DGRID)
#define NBATCH 2
#define NPTS 150000
#define NROWS (NBATCH * NPTS)
#define NPAD 300032            // ceil(NROWS/64)*64
#define NWAVES (NPAD / 64)     // 4688
#define NCBLK (NWAVES / 4)     // 1172 conv blocks (4 waves each)
#define EPSBN 1e-4f
#define SBLK 1024

typedef __attribute__((ext_vector_type(8))) short s16x8;
typedef __attribute__((ext_vector_type(4))) float f32x4;

static __device__ __forceinline__ uint32_t f2bf_rne(float f) {
  uint32_t b = __float_as_uint(f);
  return (b + 0x7FFFu + ((b >> 16) & 1u)) >> 16;
}

static __device__ __forceinline__ f32x4 mfma16(uint4 a, uint4 b, f32x4 c) {
  return __builtin_amdgcn_mfma_f32_16x16x32_bf16(
      __builtin_bit_cast(s16x8, a), __builtin_bit_cast(s16x8, b), c, 0, 0, 0);
}

// scatter point indices into dense voxel LUT (codes unique per sample)
__global__ void k_scatter(const int* __restrict__ pos, int* __restrict__ lut) {
  int g = blockIdx.x * blockDim.x + threadIdx.x;
  if (g >= NROWS) return;
  int b = g / NPTS;
  int i = g - b * NPTS;
  int x = pos[3 * g], y = pos[3 * g + 1], z = pos[3 * g + 2];
  lut[(size_t)b * D3 + (x * DGRID + y) * DGRID + z] = i;
}

// dense tap-major neighbor table: nbr[t*NPAD + g] = global row of neighbor or -1
__global__ void k_nbr(const int* __restrict__ pos, const int* __restrict__ lut,
                      int* __restrict__ nbr) {
  int g = blockIdx.x * blockDim.x + threadIdx.x;
  if (g >= NROWS) return;
  int b = g / NPTS;
  int x = pos[3 * g], y = pos[3 * g + 1], z = pos[3 * g + 2];
  const int* L = lut + (size_t)b * D3;
#pragma unroll
  for (int t = 0; t < 27; ++t) {
    int nx = x + t / 9 - 1;
    int ny = y + (t / 3) % 3 - 1;
    int nz = z + t % 3 - 1;
    int v = -1;
    if ((unsigned)nx < DGRID && (unsigned)ny < DGRID && (unsigned)nz < DGRID) {
      int n = L[(nx * DGRID + ny) * DGRID + nz];
      if (n >= 0) v = b * NPTS + n;
    }
    nbr[(size_t)t * NPAD + g] = v;
  }
}

// pack W into exact mfma_16x16x32_bf16 B-fragment layout:
// Wfrag[e], e = ((cid*27+t)*2+s)*256 + nb*64 + lane : 8 bf16 = W[t][kb+j][cout],
// kb = s*32 + (lane>>4)*8, cout = nb*16 + (lane&15)
__global__ void k_wpack(const float* __restrict__ Ws, uint4* __restrict__ Wfrag) {
  int e = blockIdx.x * 256 + threadIdx.x;
  if (e >= 4 * 27 * 512) return;
  int lane = e & 63, nb = (e >> 6) & 3, s = (e >> 8) & 1, tt = e >> 9;
  int kb = s * 32 + (lane >> 4) * 8;
  int cout = nb * 16 + (lane & 15);
  const float* src = Ws + (size_t)tt * 4096;
  uint32_t p[4];
#pragma unroll
  for (int j = 0; j < 4; ++j) {
    uint32_t lo = f2bf_rne(src[(kb + 2 * j) * 64 + cout]);
    uint32_t hi = f2bf_rne(src[(kb + 2 * j + 1) * 64 + cout]);
    p[j] = (hi << 16) | lo;
  }
  uint4 o;
  o.x = p[0]; o.y = p[1]; o.z = p[2]; o.w = p[3];
  Wfrag[e] = o;
}

// stage-1 BN stats over a f32 [NROWS][64] tensor (used for feats only)
__global__ void k_stats1(const float* __restrict__ X, float* __restrict__ part) {
  __shared__ float s[512];
  int c = threadIdx.x & 63, q = threadIdx.x >> 6;
  float sm = 0.f, sq = 0.f;
  for (int r = blockIdx.x * 4 + q; r < NROWS; r += SBLK * 4) {
    float v = X[(size_t)r * 64 + c];
    sm += v;
    sq += v * v;
  }
  s[threadIdx.x] = sm;
  s[256 + threadIdx.x] = sq;
  __syncthreads();
  if (q == 0) {
    sm = s[c] + s[64 + c] + s[128 + c] + s[192 + c];
    sq = s[256 + c] + s[320 + c] + s[384 + c] + s[448 + c];
    part[blockIdx.x * 128 + c] = sm;
    part[blockIdx.x * 128 + 64 + c] = sq;
  }
}

// stage-2: reduce nblk partials -> affine (a, b') with bnrelu(x)=relu(x*a+b')
__global__ void k_stats2(const float* __restrict__ part, int nblk,
                         const float* __restrict__ gamma, const float* __restrict__ beta,
                         float* __restrict__ chanp, int cid) {
  __shared__ float s[512];
  int c = threadIdx.x & 63, q = threadIdx.x >> 6;
  float sm = 0.f, sq = 0.f;
  for (int rb = q; rb < nblk; rb += 4) {
    sm += part[rb * 128 + c];
    sq += part[rb * 128 + 64 + c];
  }
  s[threadIdx.x] = sm;
  s[256 + threadIdx.x] = sq;
  __syncthreads();
  if (q == 0) {
    sm = s[c] + s[64 + c] + s[128 + c] + s[192 + c];
    sq = s[256 + c] + s[320 + c] + s[384 + c] + s[448 + c];
    float mean = sm / (float)NROWS;
    float var = sq / (float)NROWS - mean * mean;
    float a = gamma[cid * 64 + c] * rsqrtf(var + EPSBN);
    chanp[cid * 128 + c] = a;
    chanp[cid * 128 + 64 + c] = beta[cid * 64 + c] - mean * a;
  }
}

// h = bnrelu(X) cast to bf16, rows of 64 -> [NPAD][8] uint4
__global__ void k_hpass(const float* __restrict__ X, const float* __restrict__ chanp,
                        int cid, uint4* __restrict__ h) {
  int g = blockIdx.x * blockDim.x + threadIdx.x;
  if (g >= NROWS * 8) return;
  int c0 = (g & 7) * 8;
  const float* cp = chanp + cid * 128;
  const float4 a0 = *(const float4*)(cp + c0);
  const float4 a1 = *(const float4*)(cp + c0 + 4);
  const float4 b0 = *(const float4*)(cp + 64 + c0);
  const float4 b1 = *(const float4*)(cp + 64 + c0 + 4);
  const float4 x0 = *(const float4*)(X + (size_t)g * 8);
  const float4 x1 = *(const float4*)(X + (size_t)g * 8 + 4);
  float v0 = fmaxf(fmaf(x0.x, a0.x, b0.x), 0.f);
  float v1 = fmaxf(fmaf(x0.y, a0.y, b0.y), 0.f);
  float v2 = fmaxf(fmaf(x0.z, a0.z, b0.z), 0.f);
  float v3 = fmaxf(fmaf(x0.w, a0.w, b0.w), 0.f);
  float v4 = fmaxf(fmaf(x1.x, a1.x, b1.x), 0.f);
  float v5 = fmaxf(fmaf(x1.y, a1.y, b1.y), 0.f);
  float v6 = fmaxf(fmaf(x1.z, a1.z, b1.z), 0.f);
  float v7 = fmaxf(fmaf(x1.w, a1.w, b1.w), 0.f);
  uint4 o;
  o.x = (f2bf_rne(v1) << 16) | f2bf_rne(v0);
  o.y = (f2bf_rne(v3) << 16) | f2bf_rne(v2);
  o.z = (f2bf_rne(v5) << 16) | f2bf_rne(v4);
  o.w = (f2bf_rne(v7) << 16) | f2bf_rne(v6);
  h[g] = o;
}

// MFMA conv: wave = 64 output points x 64 cout, dense 27-tap loop,
// missing neighbors -> zero A rows. W fragments LDS-staged per tap (double buf).
// Epilogue fuses residual add + next-BN stats partials.
__global__ __launch_bounds__(256, 4) void k_conv(
    const uint4* __restrict__ h, const uint4* __restrict__ Wf,
    const int* __restrict__ nbr, const float* __restrict__ res,
    float* __restrict__ out, float* __restrict__ part, int do_stats) {
  __shared__ uint4 wlds[2][512];
  __shared__ float sred[2][4][4][16];
  int tid = threadIdx.x;
  int wv = tid >> 6, lane = tid & 63;
  int tbase = (blockIdx.x * 4 + wv) * 64;
  int lrow = lane & 15, lkg = lane >> 4;

  f32x4 acc[4][4];
#pragma unroll
  for (int i = 0; i < 4; i++)
#pragma unroll
    for (int j = 0; j < 4; j++) acc[i][j] = (f32x4){0.f, 0.f, 0.f, 0.f};

  // stage tap 0
  wlds[0][tid] = Wf[tid];
  wlds[0][256 + tid] = Wf[256 + tid];

  int nin[4];
#pragma unroll
  for (int rt = 0; rt < 4; rt++) nin[rt] = nbr[tbase + rt * 16 + lrow];

  for (int t = 0; t < 27; t++) {
    __syncthreads();
    uint4 bf[8];
#pragma unroll
    for (int i = 0; i < 8; i++) bf[i] = wlds[t & 1][i * 64 + lane];
    uint4 nv0, nv1;
    if (t + 1 < 27) {
      nv0 = Wf[(t + 1) * 512 + tid];
      nv1 = Wf[(t + 1) * 512 + 256 + tid];
    }
    int ni[4];
#pragma unroll
    for (int rt = 0; rt < 4; rt++) ni[rt] = nin[rt];
    if (t + 1 < 27) {
#pragma unroll
      for (int rt = 0; rt < 4; rt++)
        nin[rt] = nbr[(size_t)(t + 1) * NPAD + tbase + rt * 16 + lrow];
    }
#pragma unroll
    for (int rt = 0; rt < 4; rt++) {
      uint4 a0 = {0u, 0u, 0u, 0u}, a1 = {0u, 0u, 0u, 0u};
      if (ni[rt] >= 0) {
        const uint4* hp = h + (size_t)ni[rt] * 8;
        a0 = hp[lkg];
        a1 = hp[lkg + 4];
      }
#pragma unroll
      for (int nb = 0; nb < 4; nb++) {
        acc[rt][nb] = mfma16(a0, bf[nb], acc[rt][nb]);
        acc[rt][nb] = mfma16(a1, bf[4 + nb], acc[rt][nb]);
      }
    }
    if (t + 1 < 27) {
      wlds[(t + 1) & 1][tid] = nv0;
      wlds[(t + 1) & 1][256 + tid] = nv1;
    }
  }

  // epilogue: C/D layout col=lane&15, row=(lane>>4)*4+reg
  float sm[4] = {0.f, 0.f, 0.f, 0.f}, sq[4] = {0.f, 0.f, 0.f, 0.f};
#pragma unroll
  for (int rt = 0; rt < 4; rt++)
#pragma unroll
    for (int r = 0; r < 4; r++) {
      int gr = tbase + rt * 16 + lkg * 4 + r;
      if (gr < NROWS) {
#pragma unroll
        for (int nb = 0; nb < 4; nb++) {
          float v = acc[rt][nb][r];
          size_t oi = (size_t)gr * 64 + nb * 16 + lrow;
          if (res) v += res[oi];
          out[oi] = v;
          sm[nb] += v;
          sq[nb] += v * v;
        }
      }
    }
  if (do_stats) {
#pragma unroll
    for (int nb = 0; nb < 4; nb++) {
      sm[nb] += __shfl_xor(sm[nb], 16, 64);
      sm[nb] += __shfl_xor(sm[nb], 32, 64);
      sq[nb] += __shfl_xor(sq[nb], 16, 64);
      sq[nb] += __shfl_xor(sq[nb], 32, 64);
    }
    if (lane < 16) {
#pragma unroll
      for (int nb = 0; nb < 4; nb++) {
        sred[0][wv][nb][lane] = sm[nb];
        sred[1][wv][nb][lane] = sq[nb];
      }
    }
    __syncthreads();
    if (tid < 64) {
      float s0 = 0.f, s1 = 0.f;
      int nb = tid >> 4, c = tid & 15;
#pragma unroll
      for (int w = 0; w < 4; w++) {
        s0 += sred[0][w][nb][c];
        s1 += sred[1][w][nb][c];
      }
      part[blockIdx.x * 128 + tid] = s0;
      part[blockIdx.x * 128 + 64 + tid] = s1;
    }
  }
}

extern "C" void kernel_launch(void* const* d_in, const int* in_sizes, int n_in,
                              void* d_out, int out_size, void* d_ws, size_t ws_size,
                              hipStream_t stream) {
  const float* feats = (const float*)d_in[0];
  const float* Ws = (const float*)d_in[1];
  const float* gammas = (const float*)d_in[2];
  const float* betas = (const float*)d_in[3];
  const int* pos = (const int*)d_in[4];
  float* out = (float*)d_out;

  char* w = (char*)d_ws;
  auto alloc = [&](size_t b) {
    char* p = w;
    w += (b + 255) & ~(size_t)255;
    return p;
  };
  int* nbr = (int*)alloc((size_t)27 * NPAD * 4);           // 32.4 MB
  uint4* Wfrag = (uint4*)alloc((size_t)4 * 27 * 512 * 16); // 0.9 MB
  float* part = (float*)alloc((size_t)NCBLK * 128 * 4);    // 0.6 MB
  float* chanp = (float*)alloc((size_t)4 * 128 * 4);       // 2 KB
  uint4* h = (uint4*)alloc((size_t)NPAD * 128);            // 38.4 MB
  float* xbuf = (float*)alloc((size_t)NROWS * 64 * 4);     // 76.8 MB
  char* reg0 = alloc((size_t)NROWS * 64 * 4);              // 76.8 MB (cbuf overlays lut)
  float* cbuf = (float*)reg0;
  int* lut = (int*)reg0;  // lut (16.8 MB) dead before cbuf first written

  hipMemsetAsync(lut, 0xFF, (size_t)NBATCH * D3 * 4, stream);
  hipMemsetAsync(nbr, 0xFF, (size_t)27 * NPAD * 4, stream);
  int gpts = (NROWS + 255) / 256;
  k_scatter<<<gpts, 256, 0, stream>>>(pos, lut);
  k_nbr<<<gpts, 256, 0, stream>>>(pos, lut, nbr);
  k_wpack<<<216, 256, 0, stream>>>(Ws, Wfrag);

  k_stats1<<<SBLK, 256, 0, stream>>>(feats, part);
  k_stats2<<<1, 256, 0, stream>>>(part, SBLK, gammas, betas, chanp, 0);
  k_hpass<<<9375, 256, 0, stream>>>(feats, chanp, 0, h);
  k_conv<<<NCBLK, 256, 0, stream>>>(h, Wfrag + 0 * 27 * 512, nbr, nullptr, cbuf, part, 1);

  k_stats2<<<1, 256, 0, stream>>>(part, NCBLK, gammas, betas, chanp, 1);
  k_hpass<<<9375, 256, 0, stream>>>(cbuf, chanp, 1, h);
  k_conv<<<NCBLK, 256, 0, stream>>>(h, Wfrag + 1 * 27 * 512, nbr, feats, xbuf, part, 1);

  k_stats2<<<1, 256, 0, stream>>>(part, NCBLK, gammas, betas, chanp, 2);
  k_hpass<<<9375, 256, 0, stream>>>(xbuf, chanp, 2, h);
  k_conv<<<NCBLK, 256, 0, stream>>>(h, Wfrag + 2 * 27 * 512, nbr, nullptr, cbuf, part, 1);

  k_stats2<<<1, 256, 0, stream>>>(part, NCBLK, gammas, betas, chanp, 3);
  k_hpass<<<9375, 256, 0, stream>>>(cbuf, chanp, 3, h);
  k_conv<<<NCBLK, 256, 0, stream>>>(h, Wfrag + 3 * 27 * 512, nbr, xbuf, out, part, 0);
}

// Round 3
// 1188.365 us; speedup vs baseline: 1.8164x; 1.2435x over previous
//
#include <hip/hip_runtime.h>
#include <stdint.h>

#define DGRID 128
#define D3 (DGRID * DGRID * DGRID)
#define NBATCH 2
#define NPTS 150000
#define NROWS (NBATCH * NPTS)
#define NPAD 300032            // ceil(NROWS/64)*64
#define ZROW NROWS             // dedicated all-zero row of h
#define NCBLK (NPAD / 256)     // 1172 conv blocks (4 waves x 64 rows)
#define EPSBN 1e-4f
#define SBLK 1024

typedef __attribute__((ext_vector_type(8))) short s16x8;
typedef __attribute__((ext_vector_type(4))) float f32x4;

static __device__ __forceinline__ uint32_t f2bf_rne(float f) {
  uint32_t b = __float_as_uint(f);
  return (b + 0x7FFFu + ((b >> 16) & 1u)) >> 16;
}

static __device__ __forceinline__ f32x4 mfma16(uint4 a, uint4 b, f32x4 c) {
  return __builtin_amdgcn_mfma_f32_16x16x32_bf16(
      __builtin_bit_cast(s16x8, a), __builtin_bit_cast(s16x8, b), c, 0, 0, 0);
}

// scatter point indices into dense voxel LUT (codes unique per sample)
__global__ void k_scatter(const int* __restrict__ pos, int* __restrict__ lut) {
  int g = blockIdx.x * blockDim.x + threadIdx.x;
  if (g >= NROWS) return;
  int b = g / NPTS;
  int i = g - b * NPTS;
  int x = pos[3 * g], y = pos[3 * g + 1], z = pos[3 * g + 2];
  lut[(size_t)b * D3 + (x * DGRID + y) * DGRID + z] = i;
}

// dense tap-major neighbor table; invalid/missing/pad -> ZROW (zero row)
__global__ void k_nbr(const int* __restrict__ pos, const int* __restrict__ lut,
                      int* __restrict__ nbr) {
  int g = blockIdx.x * blockDim.x + threadIdx.x;
  if (g >= NPAD) return;
  if (g >= NROWS) {
#pragma unroll
    for (int t = 0; t < 27; ++t) nbr[(size_t)t * NPAD + g] = ZROW;
    return;
  }
  int b = g / NPTS;
  int x = pos[3 * g], y = pos[3 * g + 1], z = pos[3 * g + 2];
  const int* L = lut + (size_t)b * D3;
#pragma unroll
  for (int t = 0; t < 27; ++t) {
    int nx = x + t / 9 - 1;
    int ny = y + (t / 3) % 3 - 1;
    int nz = z + t % 3 - 1;
    int v = ZROW;
    if ((unsigned)nx < DGRID && (unsigned)ny < DGRID && (unsigned)nz < DGRID) {
      int n = L[(nx * DGRID + ny) * DGRID + nz];
      if (n >= 0) v = b * NPTS + n;
    }
    nbr[(size_t)t * NPAD + g] = v;
  }
}

// pack W into exact mfma_16x16x32_bf16 B-fragment layout:
// Wfrag[((cid*27+t)*2+s)*256 + nb*64 + lane]
__global__ void k_wpack(const float* __restrict__ Ws, uint4* __restrict__ Wfrag) {
  int e = blockIdx.x * 256 + threadIdx.x;
  if (e >= 4 * 27 * 512) return;
  int lane = e & 63, nb = (e >> 6) & 3, s = (e >> 8) & 1, tt = e >> 9;
  int kb = s * 32 + (lane >> 4) * 8;
  int cout = nb * 16 + (lane & 15);
  const float* src = Ws + (size_t)tt * 4096;
  uint32_t p[4];
#pragma unroll
  for (int j = 0; j < 4; ++j) {
    uint32_t lo = f2bf_rne(src[(kb + 2 * j) * 64 + cout]);
    uint32_t hi = f2bf_rne(src[(kb + 2 * j + 1) * 64 + cout]);
    p[j] = (hi << 16) | lo;
  }
  uint4 o;
  o.x = p[0]; o.y = p[1]; o.z = p[2]; o.w = p[3];
  Wfrag[e] = o;
}

// stage-1 BN stats over a f32 [NROWS][64] tensor (feats only)
__global__ void k_stats1(const float* __restrict__ X, float* __restrict__ part) {
  __shared__ float s[512];
  int c = threadIdx.x & 63, q = threadIdx.x >> 6;
  float sm = 0.f, sq = 0.f;
  for (int r = blockIdx.x * 4 + q; r < NROWS; r += SBLK * 4) {
    float v = X[(size_t)r * 64 + c];
    sm += v;
    sq += v * v;
  }
  s[threadIdx.x] = sm;
  s[256 + threadIdx.x] = sq;
  __syncthreads();
  if (q == 0) {
    sm = s[c] + s[64 + c] + s[128 + c] + s[192 + c];
    sq = s[256 + c] + s[320 + c] + s[384 + c] + s[448 + c];
    part[blockIdx.x * 128 + c] = sm;
    part[blockIdx.x * 128 + 64 + c] = sq;
  }
}

// stage-2: reduce nblk partials -> affine (a, b') with bnrelu(x)=relu(x*a+b')
__global__ void k_stats2(const float* __restrict__ part, int nblk,
                         const float* __restrict__ gamma, const float* __restrict__ beta,
                         float* __restrict__ chanp, int cid) {
  __shared__ float s[512];
  int c = threadIdx.x & 63, q = threadIdx.x >> 6;
  float sm = 0.f, sq = 0.f;
  for (int rb = q; rb < nblk; rb += 4) {
    sm += part[rb * 128 + c];
    sq += part[rb * 128 + 64 + c];
  }
  s[threadIdx.x] = sm;
  s[256 + threadIdx.x] = sq;
  __syncthreads();
  if (q == 0) {
    sm = s[c] + s[64 + c] + s[128 + c] + s[192 + c];
    sq = s[256 + c] + s[320 + c] + s[384 + c] + s[448 + c];
    float mean = sm / (float)NROWS;
    float var = sq / (float)NROWS - mean * mean;
    float a = gamma[cid * 64 + c] * rsqrtf(var + EPSBN);
    chanp[cid * 128 + c] = a;
    chanp[cid * 128 + 64 + c] = beta[cid * 64 + c] - mean * a;
  }
}

// h = bnrelu(X) cast to bf16 rows of 64 -> [NPAD][8] uint4; row ZROW = zeros
__global__ void k_hpass(const float* __restrict__ X, const float* __restrict__ chanp,
                        int cid, uint4* __restrict__ h) {
  int g = blockIdx.x * blockDim.x + threadIdx.x;
  if (g >= (NROWS + 1) * 8) return;
  if (g >= NROWS * 8) {
    h[g] = (uint4){0u, 0u, 0u, 0u};
    return;
  }
  int c0 = (g & 7) * 8;
  const float* cp = chanp + cid * 128;
  const float4 a0 = *(const float4*)(cp + c0);
  const float4 a1 = *(const float4*)(cp + c0 + 4);
  const float4 b0 = *(const float4*)(cp + 64 + c0);
  const float4 b1 = *(const float4*)(cp + 64 + c0 + 4);
  const float4 x0 = *(const float4*)(X + (size_t)g * 8);
  const float4 x1 = *(const float4*)(X + (size_t)g * 8 + 4);
  float v0 = fmaxf(fmaf(x0.x, a0.x, b0.x), 0.f);
  float v1 = fmaxf(fmaf(x0.y, a0.y, b0.y), 0.f);
  float v2 = fmaxf(fmaf(x0.z, a0.z, b0.z), 0.f);
  float v3 = fmaxf(fmaf(x0.w, a0.w, b0.w), 0.f);
  float v4 = fmaxf(fmaf(x1.x, a1.x, b1.x), 0.f);
  float v5 = fmaxf(fmaf(x1.y, a1.y, b1.y), 0.f);
  float v6 = fmaxf(fmaf(x1.z, a1.z, b1.z), 0.f);
  float v7 = fmaxf(fmaf(x1.w, a1.w, b1.w), 0.f);
  uint4 o;
  o.x = (f2bf_rne(v1) << 16) | f2bf_rne(v0);
  o.y = (f2bf_rne(v3) << 16) | f2bf_rne(v2);
  o.z = (f2bf_rne(v5) << 16) | f2bf_rne(v4);
  o.w = (f2bf_rne(v7) << 16) | f2bf_rne(v6);
  h[g] = o;
}

#define MFMA_HALF(AREG, WOFF)                                            \
  {                                                                      \
    uint4 wf[4];                                                         \
    _Pragma("unroll") for (int nb = 0; nb < 4; nb++) wf[nb] =            \
        Wt[(WOFF) + nb * 64];                                            \
    _Pragma("unroll") for (int rt = 0; rt < 4; rt++)                     \
        _Pragma("unroll") for (int nb = 0; nb < 4; nb++) acc[rt][nb] =   \
            mfma16(AREG, wf[nb], acc[rt][nb]);                           \
  }

// MFMA conv: wave = 64 rows x 64 cout; dense 27 taps; branchless zero-row
// gathers; ni 2 taps ahead, A-frags 1 tap ahead; W JIT from L1; no barriers
// in the loop. Epilogue: LDS transpose -> coalesced res/out + fused stats.
__global__ __launch_bounds__(256) void k_conv(
    const uint4* __restrict__ h, const uint4* __restrict__ Wf,
    const int* __restrict__ nbr, const float* __restrict__ res,
    float* __restrict__ out, float* __restrict__ part, int do_stats) {
  __shared__ float xp[4][16 * 68];
  __shared__ float sred[2][4][4][16];
  int tid = threadIdx.x, wv = tid >> 6, lane = tid & 63;
  int tbase = (blockIdx.x * 4 + wv) * 64;
  int lrow = lane & 15, lkg = lane >> 4;

  f32x4 acc[4][4];
#pragma unroll
  for (int i = 0; i < 4; i++)
#pragma unroll
    for (int j = 0; j < 4; j++) acc[i][j] = (f32x4){0.f, 0.f, 0.f, 0.f};

  const int* nb0 = nbr + tbase + lrow;
  int niA[4], niB[4];
  uint4 aA[4][2], aB[4][2];
#pragma unroll
  for (int rt = 0; rt < 4; rt++) niA[rt] = nb0[rt * 16];
#pragma unroll
  for (int rt = 0; rt < 4; rt++) {
    const uint4* hp = h + (size_t)niA[rt] * 8 + lkg;
    aA[rt][0] = hp[0];
    aA[rt][1] = hp[4];
  }
#pragma unroll
  for (int rt = 0; rt < 4; rt++) niB[rt] = nb0[(size_t)NPAD + rt * 16];

  for (int t = 0; t < 26; t += 2) {
    // ---- tap t (uses aA); prefetch ni(t+2), A(t+1)
#pragma unroll
    for (int rt = 0; rt < 4; rt++) niA[rt] = nb0[(size_t)(t + 2) * NPAD + rt * 16];
#pragma unroll
    for (int rt = 0; rt < 4; rt++) {
      const uint4* hp = h + (size_t)niB[rt] * 8 + lkg;
      aB[rt][0] = hp[0];
      aB[rt][1] = hp[4];
    }
    {
      const uint4* Wt = Wf + (size_t)t * 512 + lane;
      MFMA_HALF(aA[rt][0], 0)
      MFMA_HALF(aA[rt][1], 256)
    }
    // ---- tap t+1 (uses aB); prefetch ni(t+3), A(t+2)
    int t3 = (t + 3 < 27) ? t + 3 : 26;
#pragma unroll
    for (int rt = 0; rt < 4; rt++) niB[rt] = nb0[(size_t)t3 * NPAD + rt * 16];
#pragma unroll
    for (int rt = 0; rt < 4; rt++) {
      const uint4* hp = h + (size_t)niA[rt] * 8 + lkg;
      aA[rt][0] = hp[0];
      aA[rt][1] = hp[4];
    }
    {
      const uint4* Wt = Wf + (size_t)(t + 1) * 512 + lane;
      MFMA_HALF(aB[rt][0], 0)
      MFMA_HALF(aB[rt][1], 256)
    }
  }
  {  // tail tap 26 (uses aA)
    const uint4* Wt = Wf + (size_t)26 * 512 + lane;
    MFMA_HALF(aA[rt][0], 0)
    MFMA_HALF(aA[rt][1], 256)
  }

  // ---- epilogue: per-rt LDS transpose -> coalesced res/out, fused stats
  float smc[16], sqc[16];
#pragma unroll
  for (int j = 0; j < 16; j++) smc[j] = sqc[j] = 0.f;
  float* slab = xp[wv];
#pragma unroll 1
  for (int rt = 0; rt < 4; rt++) {
#pragma unroll
    for (int nb = 0; nb < 4; nb++)
#pragma unroll
      for (int r = 0; r < 4; r++)
        slab[(lkg * 4 + r) * 68 + nb * 16 + lrow] = acc[rt][nb][r];
    __syncthreads();
    int gr = tbase + rt * 16 + lrow;
    if (gr < NROWS) {
#pragma unroll
      for (int j = 0; j < 4; j++) {
        float4 vv = *(float4*)&slab[lrow * 68 + lkg * 16 + j * 4];
        size_t off = (size_t)gr * 64 + lkg * 16 + j * 4;
        if (res) {
          float4 rr = *(const float4*)(res + off);
          vv.x += rr.x; vv.y += rr.y; vv.z += rr.z; vv.w += rr.w;
        }
        *(float4*)(out + off) = vv;
        smc[j * 4 + 0] += vv.x; sqc[j * 4 + 0] += vv.x * vv.x;
        smc[j * 4 + 1] += vv.y; sqc[j * 4 + 1] += vv.y * vv.y;
        smc[j * 4 + 2] += vv.z; sqc[j * 4 + 2] += vv.z * vv.z;
        smc[j * 4 + 3] += vv.w; sqc[j * 4 + 3] += vv.w * vv.w;
      }
    }
    __syncthreads();
  }
  if (do_stats) {
#pragma unroll
    for (int j = 0; j < 16; j++) {
      smc[j] += __shfl_xor(smc[j], 1); sqc[j] += __shfl_xor(sqc[j], 1);
      smc[j] += __shfl_xor(smc[j], 2); sqc[j] += __shfl_xor(sqc[j], 2);
      smc[j] += __shfl_xor(smc[j], 4); sqc[j] += __shfl_xor(sqc[j], 4);
      smc[j] += __shfl_xor(smc[j], 8); sqc[j] += __shfl_xor(sqc[j], 8);
    }
    if (lrow == 0) {
#pragma unroll
      for (int j = 0; j < 16; j++) {
        sred[0][wv][lkg][j] = smc[j];
        sred[1][wv][lkg][j] = sqc[j];
      }
    }
    __syncthreads();
    if (tid < 64) {
      float s0 = 0.f, s1 = 0.f;
      int q = tid >> 4, c = tid & 15;
#pragma unroll
      for (int w = 0; w < 4; w++) {
        s0 += sred[0][w][q][c];
        s1 += sred[1][w][q][c];
      }
      part[blockIdx.x * 128 + tid] = s0;
      part[blockIdx.x * 128 + 64 + tid] = s1;
    }
  }
}

extern "C" void kernel_launch(void* const* d_in, const int* in_sizes, int n_in,
                              void* d_out, int out_size, void* d_ws, size_t ws_size,
                              hipStream_t stream) {
  const float* feats = (const float*)d_in[0];
  const float* Ws = (const float*)d_in[1];
  const float* gammas = (const float*)d_in[2];
  const float* betas = (const float*)d_in[3];
  const int* pos = (const int*)d_in[4];
  float* out = (float*)d_out;

  char* w = (char*)d_ws;
  auto alloc = [&](size_t b) {
    char* p = w;
    w += (b + 255) & ~(size_t)255;
    return p;
  };
  int* nbr = (int*)alloc((size_t)27 * NPAD * 4);           // 32.4 MB
  uint4* Wfrag = (uint4*)alloc((size_t)4 * 27 * 512 * 16); // 0.9 MB
  float* part = (float*)alloc((size_t)NCBLK * 128 * 4);    // 0.6 MB
  float* chanp = (float*)alloc((size_t)4 * 128 * 4);       // 2 KB
  uint4* h = (uint4*)alloc((size_t)NPAD * 128);            // 38.4 MB
  float* xbuf = (float*)alloc((size_t)NROWS * 64 * 4);     // 76.8 MB
  char* reg0 = alloc((size_t)NROWS * 64 * 4);              // 76.8 MB
  float* cbuf = (float*)reg0;
  int* lut = (int*)reg0;  // lut (16.8 MB) dead before cbuf first written

  hipMemsetAsync(lut, 0xFF, (size_t)NBATCH * D3 * 4, stream);
  int gpts = (NROWS + 255) / 256;
  k_scatter<<<gpts, 256, 0, stream>>>(pos, lut);
  k_nbr<<<NPAD / 256, 256, 0, stream>>>(pos, lut, nbr);
  k_wpack<<<216, 256, 0, stream>>>(Ws, Wfrag);

  k_stats1<<<SBLK, 256, 0, stream>>>(feats, part);
  k_stats2<<<1, 256, 0, stream>>>(part, SBLK, gammas, betas, chanp, 0);
  k_hpass<<<9376, 256, 0, stream>>>(feats, chanp, 0, h);
  k_conv<<<NCBLK, 256, 0, stream>>>(h, Wfrag + 0 * 27 * 512, nbr, nullptr, cbuf, part, 1);

  k_stats2<<<1, 256, 0, stream>>>(part, NCBLK, gammas, betas, chanp, 1);
  k_hpass<<<9376, 256, 0, stream>>>(cbuf, chanp, 1, h);
  k_conv<<<NCBLK, 256, 0, stream>>>(h, Wfrag + 1 * 27 * 512, nbr, feats, xbuf, part, 1);

  k_stats2<<<1, 256, 0, stream>>>(part, NCBLK, gammas, betas, chanp, 2);
  k_hpass<<<9376, 256, 0, stream>>>(xbuf, chanp, 2, h);
  k_conv<<<NCBLK, 256, 0, stream>>>(h, Wfrag + 2 * 27 * 512, nbr, nullptr, cbuf, part, 1);

  k_stats2<<<1, 256, 0, stream>>>(part, NCBLK, gammas, betas, chanp, 3);
  k_hpass<<<9376, 256, 0, stream>>>(cbuf, chanp, 3, h);
  k_conv<<<NCBLK, 256, 0, stream>>>(h, Wfrag + 3 * 27 * 512, nbr, xbuf, out, part, 0);
}